// Round 4
// baseline (160.504 us; speedup 1.0000x reference)
//
#include <hip/hip_runtime.h>
#include <stdint.h>

#define BI 128
#define BT 128
#define KIMG 36
#define LCAP 64
#define DD 1024
#define MP 48        // imgs K padded to 3x16 for MFMA alignment
#define MB 96        // rows per block = 2 padded images
#define NB 256       // cols per block = 4 captions
#define ASLOTS 384   // A region 16B-slots (96 rows x 64 B)
#define ABYTES 6144
#define STG_BYTES 22528  // one staging buffer (A 6KB + B 16KB)

typedef _Float16 h4 __attribute__((ext_vector_type(4)));
typedef _Float16 h8 __attribute__((ext_vector_type(8)));
typedef float f4 __attribute__((ext_vector_type(4)));

__device__ __forceinline__ float wave_red_sum(float v) {
#pragma unroll
  for (int o = 1; o < 64; o <<= 1) v += __shfl_xor(v, o, 64);
  return v;
}
__device__ __forceinline__ float wave_red_max(float v) {
#pragma unroll
  for (int o = 1; o < 64; o <<= 1) v = fmaxf(v, __shfl_xor(v, o, 64));
  return v;
}

// ---------------------------------------------------------------------------
// Kernel 1: add EPS, L2-normalize rows over D=1024, cast to fp16.
// imgs rows go to padded [BI][MP=48][DD] layout (rows 36..47 = 0).
// ---------------------------------------------------------------------------
__global__ __launch_bounds__(256) void norm_kernel(
    const float* __restrict__ imgs, const float* __restrict__ caps,
    _Float16* __restrict__ Ah, _Float16* __restrict__ Bh) {
  int row = blockIdx.x;
  int tid = threadIdx.x;
  const float* src;
  _Float16* dst;
  if (row < BI * MP) {
    int i = row / MP, k = row - i * MP;
    dst = Ah + (size_t)row * DD;
    if (k >= KIMG) {           // zero padding rows (block-uniform branch)
      h4 z = {};
      ((h4*)dst)[tid] = z;
      return;
    }
    src = imgs + ((size_t)i * KIMG + k) * DD;
  } else {
    int r = row - BI * MP;
    dst = Bh + (size_t)r * DD;
    src = caps + (size_t)r * DD;
  }
  float4 x = ((const float4*)src)[tid];
  x.x += 1e-6f; x.y += 1e-6f; x.z += 1e-6f; x.w += 1e-6f;
  float ss = x.x * x.x + x.y * x.y + x.z * x.z + x.w * x.w;
  ss = wave_red_sum(ss);
  __shared__ float red[4];
  int lane = tid & 63, w = tid >> 6;
  if (lane == 0) red[w] = ss;
  __syncthreads();
  float scale = rsqrtf(red[0] + red[1] + red[2] + red[3]);
  h4 o;
  o[0] = (_Float16)(x.x * scale);
  o[1] = (_Float16)(x.y * scale);
  o[2] = (_Float16)(x.z * scale);
  o[3] = (_Float16)(x.w * scale);
  ((h4*)dst)[tid] = o;
}

// ---------------------------------------------------------------------------
// Kernel 2: 2 images x 4 captions per block (96x256 tile), wave w = caption w.
// Ring-3 swizzled LDS staging, counted-vmcnt pipeline (STAGE 2 steps ahead,
// raw s_barrier, per-wave vmcnt(nch), vmcnt(0) only at last step).
// Register-resident masked-softmax epilogue.
// Swizzle: 16B-slot involution s ^= (s>>3)&7 per region; LDS dest linear,
// global source pre-swizzled (rule 21), frag reads apply same involution.
// ---------------------------------------------------------------------------
__global__ __launch_bounds__(256, 2) void sims_kernel(
    const _Float16* __restrict__ Ah, const _Float16* __restrict__ Bh,
    const int* __restrict__ img_lens, const int* __restrict__ cap_lens,
    float* __restrict__ out) {
  __shared__ char stage[3 * STG_BYTES] __attribute__((aligned(16)));

  int tid = threadIdx.x;
  int lane = tid & 63;
  int w = tid >> 6;       // wave = caption within quad
  int bx = blockIdx.x;    // caption quad 0..31
  int by = blockIdx.y;    // image pair 0..63
  int fr = lane & 15;
  int fq = lane >> 4;

  const size_t arow0 = (size_t)by * MB;    // into padded A rows
  const size_t brow0 = (size_t)bx * NB;

  // ---- staging plan: wave w owns contiguous chunks; one base ptr + stride --
  // chunks: w0:0-5 (A), w1:6-11, w2:12-16, w3:17-21 (B). 64 slots/chunk.
  int c0 = 6 * w - ((w >> 1) & (w & 1));   // {0,6,12,17}
  int nch = (w < 2) ? 6 : 5;
  int s0 = c0 * 64 + lane;
  bool isA = (w == 0);
  int srel = isA ? s0 : s0 - ASLOTS;
  int sw0 = srel ^ ((srel >> 3) & 7);
  const _Float16* gp0 =
      (isA ? Ah + arow0 * DD : Bh + brow0 * DD) + (size_t)(sw0 >> 2) * DD + (sw0 & 3) * 8;
  const int lds0 = c0 * 1024 + lane * 16;

  // ---- swizzled fragment byte offsets (k-invariant) ----
  int aoff[6], boff[4];
#pragma unroll
  for (int mi = 0; mi < 6; ++mi) {
    int s = (16 * mi + fr) * 4 + fq;
    aoff[mi] = (s ^ ((s >> 3) & 7)) * 16;
  }
#pragma unroll
  for (int ni = 0; ni < 4; ++ni) {
    int s = (64 * w + 16 * ni + fr) * 4 + fq;
    boff[ni] = ABYTES + (s ^ ((s >> 3) & 7)) * 16;
  }

  auto STAGE = [&](int buf, int k0) {
#pragma unroll
    for (int it = 0; it < 6; ++it) {
      if (it < nch) {
        __builtin_amdgcn_global_load_lds(
            (const __attribute__((address_space(1))) void*)(gp0 + (size_t)it * 16 * DD + k0),
            (__attribute__((address_space(3))) void*)(stage + buf * STG_BYTES + lds0 + it * 1024),
            16, 0, 0);
      }
    }
  };

  f4 acc[6][4] = {};

  STAGE(0, 0);
  STAGE(1, 32);

  for (int t = 0; t < 32; ++t) {
    // wait own oldest stage (buf t) landed; keep stage(t+1) in flight.
    if (t == 31) {
      asm volatile("s_waitcnt vmcnt(0)" ::: "memory");
    } else if (w < 2) {
      asm volatile("s_waitcnt vmcnt(6)" ::: "memory");
    } else {
      asm volatile("s_waitcnt vmcnt(5)" ::: "memory");
    }
    __builtin_amdgcn_s_barrier();        // all waves' stage(t) landed; step t-1
    __builtin_amdgcn_sched_barrier(0);   // reads fully consumed -> ring reuse ok

    if (t < 30) STAGE((t + 2) % 3, 32 * (t + 2));

    const char* rb = stage + (t % 3) * STG_BYTES;
    h8 af[6], bf[4];
#pragma unroll
    for (int mi = 0; mi < 6; ++mi)
      af[mi] = *(const h8*)(rb + aoff[mi]);
#pragma unroll
    for (int ni = 0; ni < 4; ++ni)
      bf[ni] = *(const h8*)(rb + boff[ni]);
#pragma unroll
    for (int mi = 0; mi < 6; ++mi)
#pragma unroll
      for (int ni = 0; ni < 4; ++ni)
        acc[mi][ni] = __builtin_amdgcn_mfma_f32_16x16x32_f16(
            af[mi], bf[ni], acc[mi][ni], 0, 0, 0);
  }

  // ---- register epilogue: C/D layout col=16*ni+fr, row=16*mi+4*fq+j ----
  int t = bx * 4 + w;
  int Lt = cap_lens[t];

#pragma unroll
  for (int img = 0; img < 2; ++img) {
    int Ki = img_lens[2 * by + img];

    float m = -1e30f;
#pragma unroll
    for (int mi = 0; mi < 3; ++mi)
#pragma unroll
      for (int ni = 0; ni < 4; ++ni)
#pragma unroll
        for (int j = 0; j < 4; ++j) {
          bool valid = (16 * mi + 4 * fq + j < Ki) && (16 * ni + fr < Lt);
          if (valid) m = fmaxf(m, acc[3 * img + mi][ni][j]);
        }
    m = wave_red_max(m);

    float rowe[3][4] = {}, rowes[3][4] = {}, cole[4] = {}, coles[4] = {};
#pragma unroll
    for (int mi = 0; mi < 3; ++mi)
#pragma unroll
      for (int ni = 0; ni < 4; ++ni)
#pragma unroll
        for (int j = 0; j < 4; ++j) {
          float s = acc[3 * img + mi][ni][j];
          bool valid = (16 * mi + 4 * fq + j < Ki) && (16 * ni + fr < Lt);
          float e = valid ? __expf((s - m) * 20.0f) : 0.f;  // 1/LAMB = 20
          float es = e * s;
          rowe[mi][j] += e;
          rowes[mi][j] += es;
          cole[ni] += e;
          coles[ni] += es;
        }

    // v2t: per row, reduce over cols (fr lanes), then accumulate rows
    float part = 0.f;
#pragma unroll
    for (int mi = 0; mi < 3; ++mi)
#pragma unroll
      for (int j = 0; j < 4; ++j) {
        float Re = rowe[mi][j], Res = rowes[mi][j];
#pragma unroll
        for (int o = 1; o < 16; o <<= 1) {
          Re += __shfl_xor(Re, o, 64);
          Res += __shfl_xor(Res, o, 64);
        }
        int row = 16 * mi + 4 * fq + j;
        if (fr == 0 && row < Ki) part += (Res / Re) * (0.5f / (float)Ki);
      }
    // t2v: per col, reduce over rows (fq lanes), then accumulate cols
#pragma unroll
    for (int ni = 0; ni < 4; ++ni) {
      float Ce = cole[ni], Ces = coles[ni];
#pragma unroll
      for (int o = 16; o < 64; o <<= 1) {
        Ce += __shfl_xor(Ce, o, 64);
        Ces += __shfl_xor(Ces, o, 64);
      }
      int l = 16 * ni + fr;
      if (fq == 0 && l < Lt) part += (Ces / Ce) * (0.5f / (float)Lt);
    }
    float sim = wave_red_sum(part);
    if (lane == 0) out[(size_t)(2 * by + img) * BT + t] = sim;
  }
}

extern "C" void kernel_launch(void* const* d_in, const int* in_sizes, int n_in,
                              void* d_out, int out_size, void* d_ws, size_t ws_size,
                              hipStream_t stream) {
  // setup_inputs order: img_cls, imgs, cap_cls, caps, img_lens, cap_lens
  const float* imgs = (const float*)d_in[1];
  const float* caps = (const float*)d_in[3];
  const int* img_lens = (const int*)d_in[4];
  const int* cap_lens = (const int*)d_in[5];
  float* out = (float*)d_out;

  _Float16* Ah = (_Float16*)d_ws;                    // [BI*MP][DD] = 12.6 MB
  _Float16* Bh = Ah + (size_t)BI * MP * DD;          // [BT*LCAP][DD] = 16.8 MB

  norm_kernel<<<BI * MP + BT * LCAP, 256, 0, stream>>>(imgs, caps, Ah, Bh);
  sims_kernel<<<dim3(BT / 4, BI / 2), 256, 0, stream>>>(Ah, Bh, img_lens, cap_lens, out);
}

// Round 5
// 159.011 us; speedup vs baseline: 1.0094x; 1.0094x over previous
//
#include <hip/hip_runtime.h>
#include <stdint.h>

#define BI 128
#define BT 128
#define KIMG 36
#define LCAP 64
#define DD 1024
#define MP 48        // imgs K padded to 3x16 for MFMA alignment
#define MB 96        // rows per block = 2 padded images
#define NB 256       // cols per block = 4 captions
#define ASLOTS 384   // A region 16B-slots (96 rows x 64 B)
#define ABYTES 6144
#define STG_BYTES 22528  // one staging buffer (A 6KB + B 16KB)

typedef _Float16 h4 __attribute__((ext_vector_type(4)));
typedef _Float16 h8 __attribute__((ext_vector_type(8)));
typedef float f4 __attribute__((ext_vector_type(4)));

__device__ __forceinline__ float wave_red_sum(float v) {
#pragma unroll
  for (int o = 1; o < 64; o <<= 1) v += __shfl_xor(v, o, 64);
  return v;
}
__device__ __forceinline__ float wave_red_max(float v) {
#pragma unroll
  for (int o = 1; o < 64; o <<= 1) v = fmaxf(v, __shfl_xor(v, o, 64));
  return v;
}

// ---------------------------------------------------------------------------
// Kernel 1: add EPS, L2-normalize rows over D=1024, cast to fp16.
// imgs rows go to padded [BI][MP=48][DD] layout (rows 36..47 = 0).
// ---------------------------------------------------------------------------
__global__ __launch_bounds__(256) void norm_kernel(
    const float* __restrict__ imgs, const float* __restrict__ caps,
    _Float16* __restrict__ Ah, _Float16* __restrict__ Bh) {
  int row = blockIdx.x;
  int tid = threadIdx.x;
  const float* src;
  _Float16* dst;
  if (row < BI * MP) {
    int i = row / MP, k = row - i * MP;
    dst = Ah + (size_t)row * DD;
    if (k >= KIMG) {           // zero padding rows (block-uniform branch)
      h4 z = {};
      ((h4*)dst)[tid] = z;
      return;
    }
    src = imgs + ((size_t)i * KIMG + k) * DD;
  } else {
    int r = row - BI * MP;
    dst = Bh + (size_t)r * DD;
    src = caps + (size_t)r * DD;
  }
  float4 x = ((const float4*)src)[tid];
  x.x += 1e-6f; x.y += 1e-6f; x.z += 1e-6f; x.w += 1e-6f;
  float ss = x.x * x.x + x.y * x.y + x.z * x.z + x.w * x.w;
  ss = wave_red_sum(ss);
  __shared__ float red[4];
  int lane = tid & 63, w = tid >> 6;
  if (lane == 0) red[w] = ss;
  __syncthreads();
  float scale = rsqrtf(red[0] + red[1] + red[2] + red[3]);
  h4 o;
  o[0] = (_Float16)(x.x * scale);
  o[1] = (_Float16)(x.y * scale);
  o[2] = (_Float16)(x.z * scale);
  o[3] = (_Float16)(x.w * scale);
  ((h4*)dst)[tid] = o;
}

// ---------------------------------------------------------------------------
// Kernel 2: 2 images x 4 captions per block (96x256 tile), wave w = caption w.
// Ring-3 swizzled LDS staging + REGISTER-double-buffered fragments:
// step t computes MFMA(frags_t) while ds_reading frags_{t+1} from buf(t+1).
// Per step: vmcnt(0) [drains stage(t+1), issued 1 step ago] -> s_barrier ->
// STAGE(t+2) -> setprio(1) -> {reads || MFMA clusters} -> setprio(0).
// Swizzle: 16B-slot involution s ^= (s>>3)&7 per region; LDS dest linear,
// global source pre-swizzled (rule 21), frag reads apply same involution.
// ---------------------------------------------------------------------------
__global__ __launch_bounds__(256, 2) void sims_kernel(
    const _Float16* __restrict__ Ah, const _Float16* __restrict__ Bh,
    const int* __restrict__ img_lens, const int* __restrict__ cap_lens,
    float* __restrict__ out) {
  __shared__ char stage[3 * STG_BYTES] __attribute__((aligned(16)));

  int tid = threadIdx.x;
  int lane = tid & 63;
  int w = tid >> 6;       // wave = caption within quad
  int bx = blockIdx.x;    // caption quad 0..31
  int by = blockIdx.y;    // image pair 0..63
  int fr = lane & 15;
  int fq = lane >> 4;

  const size_t arow0 = (size_t)by * MB;    // into padded A rows
  const size_t brow0 = (size_t)bx * NB;

  // ---- staging plan: wave w owns contiguous chunks; one base ptr + stride --
  // chunks: w0:0-5 (A), w1:6-11, w2:12-16, w3:17-21 (B). 64 slots/chunk.
  int c0 = 6 * w - ((w >> 1) & (w & 1));   // {0,6,12,17}
  int nch = (w < 2) ? 6 : 5;
  int s0 = c0 * 64 + lane;
  bool isA = (w == 0);
  int srel = isA ? s0 : s0 - ASLOTS;
  int sw0 = srel ^ ((srel >> 3) & 7);
  const _Float16* gp0 =
      (isA ? Ah + arow0 * DD : Bh + brow0 * DD) + (size_t)(sw0 >> 2) * DD + (sw0 & 3) * 8;
  const int lds0 = c0 * 1024 + lane * 16;

  // ---- swizzled fragment byte offsets (k-invariant) ----
  int aoff[6], boff[4];
#pragma unroll
  for (int mi = 0; mi < 6; ++mi) {
    int s = (16 * mi + fr) * 4 + fq;
    aoff[mi] = (s ^ ((s >> 3) & 7)) * 16;
  }
#pragma unroll
  for (int ni = 0; ni < 4; ++ni) {
    int s = (64 * w + 16 * ni + fr) * 4 + fq;
    boff[ni] = ABYTES + (s ^ ((s >> 3) & 7)) * 16;
  }

  auto STAGE = [&](int buf, int k0) {
#pragma unroll
    for (int it = 0; it < 6; ++it) {
      if (it < nch) {
        __builtin_amdgcn_global_load_lds(
            (const __attribute__((address_space(1))) void*)(gp0 + (size_t)it * 16 * DD + k0),
            (__attribute__((address_space(3))) void*)(stage + buf * STG_BYTES + lds0 + it * 1024),
            16, 0, 0);
      }
    }
  };

  f4 acc[6][4] = {};
  h8 afA[6], bfA[4], afB[6], bfB[4];

  // frag-set read (whole set; used in prologue / step-30)
  auto READF = [&](const char* rb, h8 (&af)[6], h8 (&bf)[4]) {
#pragma unroll
    for (int mi = 0; mi < 6; ++mi) af[mi] = *(const h8*)(rb + aoff[mi]);
#pragma unroll
    for (int ni = 0; ni < 4; ++ni) bf[ni] = *(const h8*)(rb + boff[ni]);
  };

  // one pipelined step: MFMA(cur) interleaved with reads of frags(t+1)->nxt
  auto STEP = [&](int t, h8 (&afc)[6], h8 (&bfc)[4], h8 (&afn)[6], h8 (&bfn)[4]) {
    asm volatile("s_waitcnt vmcnt(0)" ::: "memory");  // own stage(t+1) landed
    __builtin_amdgcn_s_barrier();                     // all waves' stage(t+1) in
    STAGE((t + 2) % 3, 32 * (t + 2));                 // refill freed ring slot
    const char* rb = stage + ((t + 1) % 3) * STG_BYTES;
    __builtin_amdgcn_s_setprio(1);
    // cluster ni=0: prefetch afn[0..2], compute with bfc[0]
    afn[0] = *(const h8*)(rb + aoff[0]);
    afn[1] = *(const h8*)(rb + aoff[1]);
    afn[2] = *(const h8*)(rb + aoff[2]);
#pragma unroll
    for (int mi = 0; mi < 6; ++mi)
      acc[mi][0] = __builtin_amdgcn_mfma_f32_16x16x32_f16(afc[mi], bfc[0], acc[mi][0], 0, 0, 0);
    // cluster ni=1: prefetch afn[3..5]
    afn[3] = *(const h8*)(rb + aoff[3]);
    afn[4] = *(const h8*)(rb + aoff[4]);
    afn[5] = *(const h8*)(rb + aoff[5]);
#pragma unroll
    for (int mi = 0; mi < 6; ++mi)
      acc[mi][1] = __builtin_amdgcn_mfma_f32_16x16x32_f16(afc[mi], bfc[1], acc[mi][1], 0, 0, 0);
    // cluster ni=2: prefetch bfn[0..1]
    bfn[0] = *(const h8*)(rb + boff[0]);
    bfn[1] = *(const h8*)(rb + boff[1]);
#pragma unroll
    for (int mi = 0; mi < 6; ++mi)
      acc[mi][2] = __builtin_amdgcn_mfma_f32_16x16x32_f16(afc[mi], bfc[2], acc[mi][2], 0, 0, 0);
    // cluster ni=3: prefetch bfn[2..3]
    bfn[2] = *(const h8*)(rb + boff[2]);
    bfn[3] = *(const h8*)(rb + boff[3]);
#pragma unroll
    for (int mi = 0; mi < 6; ++mi)
      acc[mi][3] = __builtin_amdgcn_mfma_f32_16x16x32_f16(afc[mi], bfc[3], acc[mi][3], 0, 0, 0);
    __builtin_amdgcn_s_setprio(0);
  };

  auto MFMA_ONLY = [&](h8 (&afc)[6], h8 (&bfc)[4]) {
    __builtin_amdgcn_s_setprio(1);
#pragma unroll
    for (int mi = 0; mi < 6; ++mi)
#pragma unroll
      for (int ni = 0; ni < 4; ++ni)
        acc[mi][ni] = __builtin_amdgcn_mfma_f32_16x16x32_f16(afc[mi], bfc[ni], acc[mi][ni], 0, 0, 0);
    __builtin_amdgcn_s_setprio(0);
  };

  // ---- prologue: stage 0,1; read frags(0) ----
  STAGE(0, 0);
  STAGE(1, 32);
  if (w < 2) asm volatile("s_waitcnt vmcnt(6)" ::: "memory");
  else       asm volatile("s_waitcnt vmcnt(5)" ::: "memory");
  __builtin_amdgcn_s_barrier();
  READF(stage, afA, bfA);

  // ---- main loop: branch-free, last two steps peeled ----
  for (int t = 0; t < 30; t += 2) {
    STEP(t, afA, bfA, afB, bfB);
    STEP(t + 1, afB, bfB, afA, bfA);
  }
  // t = 30: stage(31) landed; read frags(31); compute frags(30)
  asm volatile("s_waitcnt vmcnt(0)" ::: "memory");
  __builtin_amdgcn_s_barrier();
  READF(stage + (31 % 3) * STG_BYTES, afB, bfB);
  MFMA_ONLY(afA, bfA);
  // t = 31
  MFMA_ONLY(afB, bfB);

  // ---- register epilogue: C/D layout col=16*ni+fr, row=16*mi+4*fq+j ----
  int t = bx * 4 + w;
  int Lt = cap_lens[t];

#pragma unroll
  for (int img = 0; img < 2; ++img) {
    int Ki = img_lens[2 * by + img];

    float m = -1e30f;
#pragma unroll
    for (int mi = 0; mi < 3; ++mi)
#pragma unroll
      for (int ni = 0; ni < 4; ++ni)
#pragma unroll
        for (int j = 0; j < 4; ++j) {
          bool valid = (16 * mi + 4 * fq + j < Ki) && (16 * ni + fr < Lt);
          if (valid) m = fmaxf(m, acc[3 * img + mi][ni][j]);
        }
    m = wave_red_max(m);

    float rowe[3][4] = {}, rowes[3][4] = {}, cole[4] = {}, coles[4] = {};
#pragma unroll
    for (int mi = 0; mi < 3; ++mi)
#pragma unroll
      for (int ni = 0; ni < 4; ++ni)
#pragma unroll
        for (int j = 0; j < 4; ++j) {
          float s = acc[3 * img + mi][ni][j];
          bool valid = (16 * mi + 4 * fq + j < Ki) && (16 * ni + fr < Lt);
          float e = valid ? __expf((s - m) * 20.0f) : 0.f;  // 1/LAMB = 20
          float es = e * s;
          rowe[mi][j] += e;
          rowes[mi][j] += es;
          cole[ni] += e;
          coles[ni] += es;
        }

    // v2t: per row, reduce over cols (fr lanes), then accumulate rows
    float part = 0.f;
#pragma unroll
    for (int mi = 0; mi < 3; ++mi)
#pragma unroll
      for (int j = 0; j < 4; ++j) {
        float Re = rowe[mi][j], Res = rowes[mi][j];
#pragma unroll
        for (int o = 1; o < 16; o <<= 1) {
          Re += __shfl_xor(Re, o, 64);
          Res += __shfl_xor(Res, o, 64);
        }
        int row = 16 * mi + 4 * fq + j;
        if (fr == 0 && row < Ki) part += (Res / Re) * (0.5f / (float)Ki);
      }
    // t2v: per col, reduce over rows (fq lanes), then accumulate cols
#pragma unroll
    for (int ni = 0; ni < 4; ++ni) {
      float Ce = cole[ni], Ces = coles[ni];
#pragma unroll
      for (int o = 16; o < 64; o <<= 1) {
        Ce += __shfl_xor(Ce, o, 64);
        Ces += __shfl_xor(Ces, o, 64);
      }
      int l = 16 * ni + fr;
      if (fq == 0 && l < Lt) part += (Ces / Ce) * (0.5f / (float)Lt);
    }
    float sim = wave_red_sum(part);
    if (lane == 0) out[(size_t)(2 * by + img) * BT + t] = sim;
  }
}

extern "C" void kernel_launch(void* const* d_in, const int* in_sizes, int n_in,
                              void* d_out, int out_size, void* d_ws, size_t ws_size,
                              hipStream_t stream) {
  // setup_inputs order: img_cls, imgs, cap_cls, caps, img_lens, cap_lens
  const float* imgs = (const float*)d_in[1];
  const float* caps = (const float*)d_in[3];
  const int* img_lens = (const int*)d_in[4];
  const int* cap_lens = (const int*)d_in[5];
  float* out = (float*)d_out;

  _Float16* Ah = (_Float16*)d_ws;                    // [BI*MP][DD] = 12.6 MB
  _Float16* Bh = Ah + (size_t)BI * MP * DD;          // [BT*LCAP][DD] = 16.8 MB

  norm_kernel<<<BI * MP + BT * LCAP, 256, 0, stream>>>(imgs, caps, Ah, Bh);
  sims_kernel<<<dim3(BT / 4, BI / 2), 256, 0, stream>>>(Ah, Bh, img_lens, cap_lens, out);
}